// Round 6
// baseline (490.837 us; speedup 1.0000x reference)
//
#include <hip/hip_runtime.h>
#include <hip/hip_bf16.h>
#include <math.h>

// Problem: x[16384][512] f32, y[2048][5][512] f32 -> softmax(x @ mean_s(y).T) [16384][2048] f32
#define QTOT 16384
#define CDIM 2048
#define DDIM 512
#define SDIM 5
#define MB   64                  // rows per block (256 blocks = 1 per CU)
#define NT   512                 // 8 waves

typedef short  s8v   __attribute__((ext_vector_type(8)));  // 8 bf16 (MFMA A/B frag)
typedef float  f32x4 __attribute__((ext_vector_type(4)));  // MFMA C/D frag

__device__ __forceinline__ unsigned short f2bf(float f) {
  unsigned int u = __float_as_uint(f);
  return (unsigned short)((u + 0x7FFFu + ((u >> 16) & 1u)) >> 16);
}
__device__ __forceinline__ float bf2f(unsigned short h) {
  return __uint_as_float(((unsigned int)h) << 16);
}
__device__ __forceinline__ void gload_lds16(const void* g, void* l) {
  __builtin_amdgcn_global_load_lds(
      (const __attribute__((address_space(1))) void*)g,
      (__attribute__((address_space(3))) void*)l, 16, 0, 0);
}

// ---------------------------------------------------------------------------
// Prep: P[c][k] = mean_s y[c][s][k]; split hi/lo bf16; stage-major frag layout:
//   byte = ((kt*128 + ctg)*2 + h)*1024 + lane*16 + j*2
// => stage (kt, cg of 16 ctg) is a contiguous 32KB block (lane = (c&15)+16*((k&31)>>3), j=k&7)
__global__ void __launch_bounds__(256)
prep_kernel(const float* __restrict__ y, unsigned short* __restrict__ bf) {
  const int t  = threadIdx.x;
  const int c0 = blockIdx.x * 8;           // 256 blocks x 8 classes
  #pragma unroll
  for (int e = 0; e < 16; ++e) {
    int flat = e * 256 + t;
    int cl   = flat >> 9;
    int k    = flat & 511;
    int c    = c0 + cl;
    const float* p = y + (size_t)c * (SDIM * DDIM) + k;
    float s = 0.f;
    #pragma unroll
    for (int ss = 0; ss < SDIM; ++ss) s += p[ss * DDIM];
    float v  = s * 0.2f;
    unsigned short hi = f2bf(v);
    unsigned short lo = f2bf(v - bf2f(hi));
    int kt   = k >> 5;
    int ctg  = c >> 4;
    int lane = (c & 15) + 16 * ((k & 31) >> 3);
    int j    = k & 7;
    size_t base = ((size_t)(kt * 128 + ctg) * 2) * 512 + lane * 8 + j;
    bf[base]       = hi;
    bf[base + 512] = lo;
  }
}

// ---------------------------------------------------------------------------
// A-quarter conversion: rows q0..q0+63, k in [kq*128, kq*128+128) -> hi/lo
// frag layout in ldsA: ushort idx ((ktL*4+mt)*2+h)*512 + lanea*8 + j0.
__device__ __forceinline__ void convertA(const float* __restrict__ x, int q0,
                                         int kq, int t, unsigned short* ldsA) {
  const float4* x4 = (const float4*)(x + (size_t)q0 * DDIM);
  #pragma unroll
  for (int i = 0; i < 4; ++i) {
    int idx = t + NT * i;                  // 2048 float4 per quarter
    int q   = idx >> 5;                    // 0..63 (32 float4 per row-quarter)
    int k4l = idx & 31;
    float4 f = x4[(size_t)q * 128 + kq * 32 + k4l];
    int ktL   = k4l >> 3;                  // 0..3
    int mt    = q >> 4;                    // 0..3
    int lanea = (q & 15) + 16 * ((k4l >> 1) & 3);
    int j0    = (k4l & 1) * 4;
    unsigned short h0 = f2bf(f.x), h1 = f2bf(f.y), h2 = f2bf(f.z), h3 = f2bf(f.w);
    unsigned short l0 = f2bf(f.x - bf2f(h0)), l1 = f2bf(f.y - bf2f(h1));
    unsigned short l2 = f2bf(f.z - bf2f(h2)), l3 = f2bf(f.w - bf2f(h3));
    *(ushort4*)&ldsA[((ktL * 4 + mt) * 2 + 0) * 512 + lanea * 8 + j0] =
        make_ushort4(h0, h1, h2, h3);
    *(ushort4*)&ldsA[((ktL * 4 + mt) * 2 + 1) * 512 + lanea * 8 + j0] =
        make_ushort4(l0, l1, l2, l3);
  }
}

#define MFMA(a, b, c) __builtin_amdgcn_mfma_f32_16x16x32_bf16(a, b, c, 0, 0, 0)

// ---------------------------------------------------------------------------
// Fused GEMM (3-pass bf16 MFMA) + row softmax. 256 blocks (1/CU):
// block = 64 rows x 2048 cols, 8 waves; wave = all 64 rows x 256 cols
// (acc 256 f32). A quarter-staged in LDS (32KB), frags in regs per kt.
// B: 128 stages of 32KB through 3 rotating LDS buffers; stage s issues
// loads for s+2 and waits vmcnt(4) (drains s+1, ~2 stages in flight).
__global__ void __launch_bounds__(NT, 2)
gemm_softmax_kernel(const float* __restrict__ x,
                    const unsigned short* __restrict__ bf,
                    float* __restrict__ out) {
  __shared__ unsigned short ldsA[16384];      // 32KB A-quarter frags
  __shared__ unsigned short ldsB[3][16384];   // 3 x 32KB B stage buffers

  const int t      = threadIdx.x;
  const int lane   = t & 63;
  const int w      = t >> 6;                  // 0..7
  const int lane16 = lane * 16;
  const int w4096  = w * 4096;
  const int q0     = blockIdx.x * MB;
  const char* bfB  = (const char*)bf;
  char* ldsBc      = (char*)&ldsB[0][0];

  // ---- prologue: issue B stages 0,1; convert A quarter 0; one full sync ----
  #pragma unroll
  for (int s = 0; s < 2; ++s) {
    const char* src = bfB + (size_t)s * 32768 + w4096 + lane16;
    char* dst = ldsBc + s * 32768 + w4096 + lane16;
    gload_lds16(src,        dst);
    gload_lds16(src + 1024, dst + 1024);
    gload_lds16(src + 2048, dst + 2048);
    gload_lds16(src + 3072, dst + 3072);
  }
  convertA(x, q0, 0, t, ldsA);
  __syncthreads();                            // A q0 + B stages 0,1 ready

  f32x4 acc[8][2][4];                         // [cg][i][mt]
  #pragma unroll
  for (int cg = 0; cg < 8; ++cg)
    #pragma unroll
    for (int i = 0; i < 2; ++i)
      #pragma unroll
      for (int mt = 0; mt < 4; ++mt) acc[cg][i][mt] = (f32x4)0.f;

  const s8v* A8s = (const s8v*)ldsA;
  int bc = 0;                                 // buffer consumed by current stage

  #pragma unroll 1
  for (int kq = 0; kq < 4; ++kq) {
    if (kq) {                                 // re-stage A quarter
      __syncthreads();
      convertA(x, q0, kq, t, ldsA);
      __syncthreads();
    }
    #pragma unroll 1
    for (int ktL = 0; ktL < 4; ++ktL) {
      // A frags for this kt into registers (8 x ds_read_b128, lane-contiguous)
      s8v ah[4], al[4];
      #pragma unroll
      for (int mt = 0; mt < 4; ++mt) {
        ah[mt] = A8s[((ktL * 4 + mt) * 2 + 0) * 64 + lane];
        al[mt] = A8s[((ktL * 4 + mt) * 2 + 1) * 64 + lane];
      }
      #pragma unroll
      for (int cg = 0; cg < 8; ++cg) {
        const int s  = kq * 32 + ktL * 8 + cg;
        int bi = bc + 2; if (bi >= 3) bi -= 3;
        // issue stage s+2 (wrap -> harmless dead reload of stage 0/1)
        {
          const char* src = bfB + (size_t)((s + 2) & 127) * 32768 + w4096 + lane16;
          char* dst = ldsBc + bi * 32768 + w4096 + lane16;
          gload_lds16(src,        dst);
          gload_lds16(src + 1024, dst + 1024);
          gload_lds16(src + 2048, dst + 2048);
          gload_lds16(src + 3072, dst + 3072);
        }
        // B frags: wave's 2 c-tiles of this stage (hi/lo), conflict-free b128
        const s8v* Bb = (const s8v*)(ldsBc + bc * 32768 + w4096 + lane16);
        s8v bh0 = Bb[0], bl0 = Bb[64], bh1 = Bb[128], bl1 = Bb[192];
        // 24 MFMA: passes hihi, lohi, hilo; 8-wide independence per pass
        __builtin_amdgcn_s_setprio(1);
        #pragma unroll
        for (int mt = 0; mt < 4; ++mt) {
          acc[cg][0][mt] = MFMA(ah[mt], bh0, acc[cg][0][mt]);
          acc[cg][1][mt] = MFMA(ah[mt], bh1, acc[cg][1][mt]);
        }
        #pragma unroll
        for (int mt = 0; mt < 4; ++mt) {
          acc[cg][0][mt] = MFMA(al[mt], bh0, acc[cg][0][mt]);
          acc[cg][1][mt] = MFMA(al[mt], bh1, acc[cg][1][mt]);
        }
        #pragma unroll
        for (int mt = 0; mt < 4; ++mt) {
          acc[cg][0][mt] = MFMA(ah[mt], bl0, acc[cg][0][mt]);
          acc[cg][1][mt] = MFMA(ah[mt], bl1, acc[cg][1][mt]);
        }
        __builtin_amdgcn_s_setprio(0);
        // counted drain: waits stage s+1's loads (issued one stage ago);
        // stage s+2's 4 remain in flight. Never vmcnt(0) in the loop.
        asm volatile("s_waitcnt vmcnt(4)" ::: "memory");
        __builtin_amdgcn_sched_barrier(0);
        __builtin_amdgcn_s_barrier();
        __builtin_amdgcn_sched_barrier(0);
        bc = (bc == 2) ? 0 : bc + 1;
      }
    }
  }
  __syncthreads();   // drain dead prefetches; ldsA free for reductions

  // ------------------- softmax over c (rows q0..q0+63) ----------------------
  // C/D: col = lane&15, row-in-16 = (lane>>4)*4 + reg. Wave cols:
  // cg*256 + w*32 + i*16 + cl; rows mt*16 + g*4 + r (all mt per wave).
  float* red = (float*)ldsA;                  // max [0,512), sum [512,1024)
  const int g  = lane >> 4;
  const int cl = lane & 15;

  float mx[4][4];
  #pragma unroll
  for (int mt = 0; mt < 4; ++mt)
    #pragma unroll
    for (int r = 0; r < 4; ++r) {
      float v = acc[0][0][mt][r];
      #pragma unroll
      for (int cg = 0; cg < 8; ++cg)
        #pragma unroll
        for (int i = 0; i < 2; ++i)
          if (cg | i) v = fmaxf(v, acc[cg][i][mt][r]);
      #pragma unroll
      for (int off = 1; off < 16; off <<= 1) v = fmaxf(v, __shfl_xor(v, off, 64));
      mx[mt][r] = v;
    }
  if (cl == 0) {
    #pragma unroll
    for (int mt = 0; mt < 4; ++mt)
      #pragma unroll
      for (int r = 0; r < 4; ++r) red[(mt * 16 + g * 4 + r) * 8 + w] = mx[mt][r];
  }
  __syncthreads();
  #pragma unroll
  for (int mt = 0; mt < 4; ++mt)
    #pragma unroll
    for (int r = 0; r < 4; ++r) {
      const float* rp = &red[(mt * 16 + g * 4 + r) * 8];
      float v = rp[0];
      #pragma unroll
      for (int ww = 1; ww < 8; ++ww) v = fmaxf(v, rp[ww]);
      mx[mt][r] = v;
    }

  float sm[4][4];
  #pragma unroll
  for (int mt = 0; mt < 4; ++mt)
    #pragma unroll
    for (int r = 0; r < 4; ++r) {
      float s = 0.f;
      #pragma unroll
      for (int cg = 0; cg < 8; ++cg)
        #pragma unroll
        for (int i = 0; i < 2; ++i) {
          float e = __expf(acc[cg][i][mt][r] - mx[mt][r]);
          acc[cg][i][mt][r] = e;
          s += e;
        }
      #pragma unroll
      for (int off = 1; off < 16; off <<= 1) s += __shfl_xor(s, off, 64);
      sm[mt][r] = s;
    }
  if (cl == 0) {
    #pragma unroll
    for (int mt = 0; mt < 4; ++mt)
      #pragma unroll
      for (int r = 0; r < 4; ++r) red[512 + (mt * 16 + g * 4 + r) * 8 + w] = sm[mt][r];
  }
  __syncthreads();

  #pragma unroll
  for (int mt = 0; mt < 4; ++mt)
    #pragma unroll
    for (int r = 0; r < 4; ++r) {
      const float* rp = &red[512 + (mt * 16 + g * 4 + r) * 8];
      float s = rp[0];
      #pragma unroll
      for (int ww = 1; ww < 8; ++ww) s += rp[ww];
      float inv = 1.0f / s;
      float* orow = out + (size_t)(q0 + mt * 16 + g * 4 + r) * CDIM + w * 32 + cl;
      #pragma unroll
      for (int cg = 0; cg < 8; ++cg)
        #pragma unroll
        for (int i = 0; i < 2; ++i)
          orow[cg * 256 + i * 16] = acc[cg][i][mt][r] * inv;
    }
}

// ---------------------------------------------------------------------------
extern "C" void kernel_launch(void* const* d_in, const int* in_sizes, int n_in,
                              void* d_out, int out_size, void* d_ws, size_t ws_size,
                              hipStream_t stream) {
  const float* x = (const float*)d_in[0];          // [16384][512]
  const float* y = (const float*)d_in[1];          // [2048][5][512]
  float* out     = (float*)d_out;                  // [16384][2048]
  unsigned short* bf = (unsigned short*)d_ws;      // Bf stage-major, 4MB

  hipLaunchKernelGGL(prep_kernel, dim3(256), dim3(256), 0, stream, y, bf);
  hipLaunchKernelGGL(gemm_softmax_kernel, dim3(QTOT / MB), dim3(NT), 0, stream,
                     x, bf, out);
}